// Round 20
// baseline (972.341 us; speedup 1.0000x reference)
//
#include <hip/hip_runtime.h>
#include <math.h>

typedef float4 f4;
typedef unsigned long long u64;
typedef __attribute__((ext_vector_type(2))) float v2f;
typedef __attribute__((ext_vector_type(4))) float v4f;
#define NW 248
#define NB 64
#define NPH2 (NW + 8)   // 256 phases; phase p: L0 step p, L1 step p-1 (window-parallel, split 2 blocks/row)

// ============================================================================
// RESUBMIT of round 19 (bench infra failed before execution: no timing dict).
// Champion (r18 packed-FP32, 883us) + ONE change: conditional early-post.
// {midbar; PRODUCE} inserted after whichever REGA contains the finishing slot
// ((gs>>1)&1 == P) -> post moves up to one PAIR earlier; standalone bar1
// removed (consumers: 2 barriers/phase, single-thread spin right after A).
// NO added REGA instantiations (r12's spill came from 3 copies; here still 2).
// Session failure catalog (all measured; do NOT retry):
//  - r8:  >1 spinner thread/block on agent atomics -> coherent-poll storm (16x).
//  - r10: 4 blocks/row -> exchange exposure doubles, 1692us.
//  - r11: RELAXED atomic spin-loads lower to per-poll writes (WRITE_SIZE 15MB).
//  - r11/r12: 3x-duplicated region-A -> VGPR 128 + scratch spill (+40%).
//  - r13: producer-only bar1 alone: neutral-negative.
//  - r14/r16: 1024thr: both occupancy knobs rejected -> 64-VGPR provision, spill.
// Health checks: VGPR <=116 + WRITE ~1.5KB = OK; VGPR >=128 or WRITE in MBs =
// spill -> revert to r18 champion. If infra fails again -> revert to r18.
// ============================================================================

__device__ __forceinline__ float tanh_f(float x) { return 2.0f * __builtin_amdgcn_rcpf(1.0f + __expf(-2.0f * x)) - 1.0f; }

template<int CTRL>
__device__ __forceinline__ float dppf(float v) {
    return __int_as_float(__builtin_amdgcn_update_dpp(0, __float_as_int(v), CTRL, 0xF, 0xF, true));
}
#define XOR1 0xB1   // quad_perm [1,0,3,2]
#define XOR2 0x4E   // quad_perm [2,3,0,1]
#define MIR7 0x141  // ROW_HALF_MIRROR: lane i -> 7-i within 8 (== xor 7)
#define BC0  0x00
#define BC1  0x55
#define BC2  0xAA
#define BC3  0xFF

#define OPQ1(X) asm volatile("" : "+v"(X));

// packed fp32 fma: acc.x += W.x*H.x; acc.y += W.y*H.y  (v_pk_fma_f32)
#define PFMA(acc,W,H) (acc) = __builtin_elementwise_fma((W), (H), (acc));
#define DOTG(N,h0,h1,h2,h3,ACC) \
  PFMA(ACC, N##0, h0) PFMA(ACC, N##1, h1) PFMA(ACC, N##2, h2) PFMA(ACC, N##3, h3)

#define LO2(V) __builtin_shufflevector((V), (V), 0, 1)
#define HI2(V) __builtin_shufflevector((V), (V), 2, 3)

#define LDW2(N, SRC, G) \
  v2f N##0 = *(const v2f*)((SRC) + (G)*4096 + jo),     \
      N##1 = *(const v2f*)((SRC) + (G)*4096 + jo + 2), \
      N##2 = *(const v2f*)((SRC) + (G)*4096 + jo + 4), \
      N##3 = *(const v2f*)((SRC) + (G)*4096 + jo + 6);
#define OPQW(N) OPQ1(N##0) OPQ1(N##1) OPQ1(N##2) OPQ1(N##3)

// Butterfly (verified invariant: reg m holds value (m&3)^q2, half bit2(m)) +
// unified activation + cell update. Uses Q0..Q7, lolane, fs2, fs3, kae from scope.
#define TAIL8(CC, SA, SB, VA, VB, HN)                                                     \
    {                                                                                     \
        float r0=dppf<XOR1>(Q1), r1=dppf<XOR1>(Q0), r2=dppf<XOR1>(Q3), r3=dppf<XOR1>(Q2); \
        float r4=dppf<XOR1>(Q5), r5=dppf<XOR1>(Q4), r6=dppf<XOR1>(Q7), r7=dppf<XOR1>(Q6); \
        Q0+=r0; Q1+=r1; Q2+=r2; Q3+=r3; Q4+=r4; Q5+=r5; Q6+=r6; Q7+=r7;                   \
        float u0=dppf<XOR2>(Q2), u3=dppf<XOR2>(Q1), u4=dppf<XOR2>(Q6), u7=dppf<XOR2>(Q5); \
        Q0+=u0; Q3+=u3; Q4+=u4; Q7+=u7;                                                   \
        float m0=dppf<MIR7>(Q3), m4=dppf<MIR7>(Q7);                                       \
        Q0+=m0; Q4+=m4;                                                                   \
        const float yv = lolane ? Q0 : Q4;                                                \
        const float av = fmaf(fs2, __builtin_amdgcn_rcpf(1.f + __expf(kae*yv)), fs3);     \
        const float gi = dppf<BC0>(av);                                                   \
        const float gf = dppf<BC1>(av);                                                   \
        const float gg = dppf<BC2>(av);                                                   \
        const float go = dppf<BC3>(av);                                                   \
        const bool rst = lolane ? ((SA)==0) : ((SB)==0);                                  \
        const bool upd = lolane ? (VA) : (VB);                                            \
        const float igv = gi * gg;                                                        \
        const float ccn = rst ? igv : fmaf(gf, CC, igv);                                  \
        CC = upd ? ccn : CC;                                                              \
        HN = go * tanh_f(CC);                                                             \
    }

// Region-A work for pair P (literal 0/1): packed L0 main gates -> QM[P], L1 full -> X1w.
#define REGA(P)                                                                            \
    {                                                                                      \
        const int cA = 4*half + 2*(P), cB = cA + 1;                                        \
        const int lA = 2*(P),          lB = lA + 1;                                        \
        const int sA0 = (p - cA) & 7,     sB0 = (p - cB) & 7;                              \
        const int sA1 = (p - 1 - cA) & 7, sB1 = (p - 1 - cB) & 7;                          \
        const bool vA1 = (unsigned)(p - 1 - sA1) < (unsigned)NW;                           \
        const bool vB1 = (unsigned)(p - 1 - sB1) < (unsigned)NW;                           \
        const v4f hAa = *(const v4f*)(X0r + lA*64), hAb = *(const v4f*)(X0r + lA*64 + 4);  \
        const v4f hBa = *(const v4f*)(X0r + lB*64), hBb = *(const v4f*)(X0r + lB*64 + 4);  \
        const v2f hA0 = LO2(hAa), hA1 = HI2(hAa), hA2 = LO2(hAb), hA3 = HI2(hAb);          \
        const v2f hB0 = LO2(hBa), hB1 = HI2(hBa), hB2 = LO2(hBb), hB3 = HI2(hBb);          \
        {   /* L0 main gates (bias + Whh0.h0; x added in region C) */                      \
            v2f a0 = {bb00, 0.f}, a1 = {bb01, 0.f}, a2 = {bb02, 0.f}, a3 = {bb03, 0.f};    \
            v2f a4 = {bb00, 0.f}, a5 = {bb01, 0.f}, a6 = {bb02, 0.f}, a7 = {bb03, 0.f};    \
            if (sA0 != 0) {                                                                \
                DOTG(W0, hA0,hA1,hA2,hA3, a0)                                              \
                DOTG(W1, hA0,hA1,hA2,hA3, a1)                                              \
                DOTG(W2, hA0,hA1,hA2,hA3, a2)                                              \
                DOTG(W3, hA0,hA1,hA2,hA3, a3)                                              \
            }                                                                              \
            if (sB0 != 0) {                                                                \
                DOTG(W0, hB0,hB1,hB2,hB3, a4)                                              \
                DOTG(W1, hB0,hB1,hB2,hB3, a5)                                              \
                DOTG(W2, hB0,hB1,hB2,hB3, a6)                                              \
                DOTG(W3, hB0,hB1,hB2,hB3, a7)                                              \
            }                                                                              \
            QM[P][0]=a0.x+a0.y; QM[P][1]=a1.x+a1.y; QM[P][2]=a2.x+a2.y; QM[P][3]=a3.x+a3.y;\
            QM[P][4]=a4.x+a4.y; QM[P][5]=a5.x+a5.y; QM[P][6]=a6.x+a6.y; QM[P][7]=a7.x+a7.y;\
        }                                                                                  \
        {   /* L1 gates: Wih1.h0(p-1) (reuse h slices) + Whh1.h1(p-2) */                   \
            v2f p0 = {bb10, 0.f}, p1 = {bb11, 0.f}, p2 = {bb12, 0.f}, p3 = {bb13, 0.f};    \
            v2f p4 = {bb10, 0.f}, p5 = {bb11, 0.f}, p6 = {bb12, 0.f}, p7 = {bb13, 0.f};    \
            DOTG(U0, hA0,hA1,hA2,hA3, p0)                                                  \
            DOTG(U1, hA0,hA1,hA2,hA3, p1)                                                  \
            DOTG(U2, hA0,hA1,hA2,hA3, p2)                                                  \
            DOTG(U3, hA0,hA1,hA2,hA3, p3)                                                  \
            DOTG(U0, hB0,hB1,hB2,hB3, p4)                                                  \
            DOTG(U1, hB0,hB1,hB2,hB3, p5)                                                  \
            DOTG(U2, hB0,hB1,hB2,hB3, p6)                                                  \
            DOTG(U3, hB0,hB1,hB2,hB3, p7)                                                  \
            if (sA1 != 0) {                                                                \
                const v4f eAa = *(const v4f*)(X1r + lA*64), eAb = *(const v4f*)(X1r + lA*64 + 4); \
                const v2f eA0 = LO2(eAa), eA1 = HI2(eAa), eA2 = LO2(eAb), eA3 = HI2(eAb);  \
                DOTG(V0, eA0,eA1,eA2,eA3, p0)                                              \
                DOTG(V1, eA0,eA1,eA2,eA3, p1)                                              \
                DOTG(V2, eA0,eA1,eA2,eA3, p2)                                              \
                DOTG(V3, eA0,eA1,eA2,eA3, p3)                                              \
            }                                                                              \
            if (sB1 != 0) {                                                                \
                const v4f eBa = *(const v4f*)(X1r + lB*64), eBb = *(const v4f*)(X1r + lB*64 + 4); \
                const v2f eB0 = LO2(eBa), eB1 = HI2(eBa), eB2 = LO2(eBb), eB3 = HI2(eBb);  \
                DOTG(V0, eB0,eB1,eB2,eB3, p4)                                              \
                DOTG(V1, eB0,eB1,eB2,eB3, p5)                                              \
                DOTG(V2, eB0,eB1,eB2,eB3, p6)                                              \
                DOTG(V3, eB0,eB1,eB2,eB3, p7)                                              \
            }                                                                              \
            float Q0 = p0.x+p0.y, Q1 = p1.x+p1.y, Q2 = p2.x+p2.y, Q3 = p3.x+p3.y;          \
            float Q4 = p4.x+p4.y, Q5 = p5.x+p5.y, Q6 = p6.x+p6.y, Q7 = p7.x+p7.y;          \
            float hn1;                                                                     \
            TAIL8(cc1[P], sA1, sB1, vA1, vB1, hn1)                                         \
            if (vA1 && idx == 0) X1w[lA*64] = hn1;                                         \
            if (vB1 && idx == 4) X1w[lB*64] = hn1;                                         \
        }                                                                                  \
    }

// Producer post (wave 0 only; called right after the finishing pair's midbar).
#define DO_PRODUCE()                                                                       \
    if (tid < 64) {                                                                        \
        const int w1_ = p - 8;                                                             \
        const float hval_ = X1[par][gs & 3][tid];                                          \
        float r0_ = wl0 * hval_, r1_ = wl1 * hval_;                                        \
        _Pragma("unroll")                                                                  \
        for (int off_ = 32; off_ > 0; off_ >>= 1) {                                        \
            r0_ += __shfl_down(r0_, off_);                                                 \
            r1_ += __shfl_down(r1_, off_);                                                 \
        }                                                                                  \
        if (tid == 0) {                                                                    \
            const float prev0_ = w1_ ? outr[(w1_-1) & 7][0] : trajS[7*4+2];                \
            const float prev1_ = w1_ ? outr[(w1_-1) & 7][1] : trajS[7*4+3];                \
            const float o0_ = prev0_ + r0_ + bl0;                                          \
            const float o1_ = prev1_ + r1_ + bl1;                                          \
            outr[w1_ & 7][0] = o0_; outr[w1_ & 7][1] = o1_;                                \
            out[((size_t)row * NW + w1_) * 2 + 0] = o0_;                                   \
            out[((size_t)row * NW + w1_) * 2 + 1] = o1_;                                   \
            u64* rp_ = ring + ((size_t)row * 16 + (p & 15)) * 2;                           \
            const unsigned tg_ = (unsigned)(p + 1);                                        \
            const u64 k0_ = ((u64)tg_ << 32) | (u64)__float_as_uint(o0_);                  \
            const u64 k1_ = ((u64)tg_ << 32) | (u64)__float_as_uint(o1_);                  \
            __hip_atomic_store(&rp_[0], k0_, __ATOMIC_RELEASE, __HIP_MEMORY_SCOPE_AGENT);  \
            __hip_atomic_store(&rp_[1], k1_, __ATOMIC_RELEASE, __HIP_MEMORY_SCOPE_AGENT);  \
        }                                                                                  \
    }

__device__ __forceinline__ float xsel4(float x0, float x1, float x2, float x3, int q2) {
    return (q2 & 2) ? ((q2 & 1) ? x3 : x2) : ((q2 & 1) ? x1 : x0);
}

// General (prologue) x-sourcing. Every outr read is row (w+s-8)&7 == (p-8)&7.
__device__ __forceinline__ float xload(const float* trajS, const float (*outr)[2],
                                       int w, int s, int q2) {
    float x0, x1, x2, x3;
    if (w == 0) {
        x0 = trajS[s*4+0]; x1 = trajS[s*4+1]; x2 = trajS[s*4+2]; x3 = trajS[s*4+3];
    } else if (w < 8) {
        if (s < 8 - w) {
            const int tt = w + s;
            x0 = trajS[tt*4+0]; x1 = trajS[tt*4+1]; x2 = trajS[tt*4+2]; x3 = trajS[tt*4+3];
        } else {
            const int tc = 2*w + s - 1;
            const int jo2 = (w + s - 8) & 7;
            x0 = trajS[tc*4+0]; x1 = trajS[tc*4+1];
            x2 = outr[jo2][0];  x3 = outr[jo2][1];
        }
    } else {
        const int tc = w + s;
        const int jo2 = (w + s) & 7;
        x0 = trajS[tc*4+0]; x1 = trajS[tc*4+1];
        x2 = outr[jo2][0];  x3 = outr[jo2][1];
    }
    return xsel4(x0, x1, x2, x3, q2);
}

// 2 blocks per row. SAME-XCD PAIRING: row = bid&63, half = bid>>6 (pair r, r+64
// both == r mod 8 -> same XCD under round-robin; perf heuristic only).
// Exchange = out[p-8] as TWO tagged u64 atomics {tag=p+1, f32}; ONE spinner/block.
__global__ __launch_bounds__(512) __attribute__((amdgpu_waves_per_eu(2, 2)))
void or_lstm_coop(const float* __restrict__ traj,
                  const float* __restrict__ Wih0, const float* __restrict__ Whh0,
                  const float* __restrict__ bih0, const float* __restrict__ bhh0,
                  const float* __restrict__ Wih1, const float* __restrict__ Whh1,
                  const float* __restrict__ bih1, const float* __restrict__ bhh1,
                  const float* __restrict__ Wlin, const float* __restrict__ blin,
                  float* __restrict__ out, u64* __restrict__ ring)
{
    const int bid  = blockIdx.x;
    const int row  = bid & 63;
    const int half = bid >> 6;        // 0: slots 0-3, 1: slots 4-7  (pair on same XCD)
    const int tid  = threadIdx.x;     // = j*8 + idx
    const int j    = tid >> 3;
    const int idx  = tid & 7;
    const int q2   = idx & 3;

    __shared__ __align__(16) float trajS[256 * 4];
    __shared__ __align__(16) float X0[2][4][64];   // [parity][local slot][j]
    __shared__ __align__(16) float X1[2][4][64];
    __shared__ float outr[8][2];                   // full ring, mirrored in both blocks

    if (tid < 256)
        ((f4*)trajS)[tid] = ((const f4*)(traj + (size_t)row * 256 * 4))[tid];
    ((float*)X0)[tid] = 0.f;                       // 2*4*64 = 512 floats each
    ((float*)X1)[tid] = 0.f;

    // ---- gate-permuted weight slices as v2 pairs (identical in both blocks) ----
    const int jo = j * 64 + idx * 8;
    const int v0 = q2, v1 = 1 ^ q2, v2 = 2 ^ q2, v3 = 3 ^ q2;
    LDW2(W0, Whh0, v0) LDW2(W1, Whh0, v1) LDW2(W2, Whh0, v2) LDW2(W3, Whh0, v3)
    LDW2(U0, Wih1, v0) LDW2(U1, Wih1, v1) LDW2(U2, Wih1, v2) LDW2(U3, Wih1, v3)
    LDW2(V0, Whh1, v0) LDW2(V1, Whh1, v1) LDW2(V2, Whh1, v2) LDW2(V3, Whh1, v3)
    OPQW(W0) OPQW(W1) OPQW(W2) OPQW(W3)
    OPQW(U0) OPQW(U1) OPQW(U2) OPQW(U3)
    OPQW(V0) OPQW(V1) OPQW(V2) OPQW(V3)

    float wx0 = (idx < 4) ? Wih0[v0*256 + j*4 + q2] : 0.f;
    float wx1 = (idx < 4) ? Wih0[v1*256 + j*4 + q2] : 0.f;
    float wx2 = (idx < 4) ? Wih0[v2*256 + j*4 + q2] : 0.f;
    float wx3 = (idx < 4) ? Wih0[v3*256 + j*4 + q2] : 0.f;
    float bb00 = (idx == 0) ? (bih0[0*64+j] + bhh0[0*64+j]) : 0.f;
    float bb01 = (idx == 0) ? (bih0[1*64+j] + bhh0[1*64+j]) : 0.f;
    float bb02 = (idx == 0) ? (bih0[2*64+j] + bhh0[2*64+j]) : 0.f;
    float bb03 = (idx == 0) ? (bih0[3*64+j] + bhh0[3*64+j]) : 0.f;
    float bb10 = (idx == 0) ? (bih1[0*64+j] + bhh1[0*64+j]) : 0.f;
    float bb11 = (idx == 0) ? (bih1[1*64+j] + bhh1[1*64+j]) : 0.f;
    float bb12 = (idx == 0) ? (bih1[2*64+j] + bhh1[2*64+j]) : 0.f;
    float bb13 = (idx == 0) ? (bih1[3*64+j] + bhh1[3*64+j]) : 0.f;
    OPQ1(wx0) OPQ1(wx1) OPQ1(wx2) OPQ1(wx3)
    OPQ1(bb00) OPQ1(bb01) OPQ1(bb02) OPQ1(bb03)
    OPQ1(bb10) OPQ1(bb11) OPQ1(bb12) OPQ1(bb13)

    const float kae = (q2 == 2) ? -2.f : -1.f;
    const float fs2 = (q2 == 2) ?  2.f :  1.f;
    const float fs3 = (q2 == 2) ? -1.f :  0.f;

    // epilogue weights: wave 0 computes BOTH output components
    float wl0 = 0.f, wl1 = 0.f;
    if (tid < 64) { wl0 = Wlin[tid]; wl1 = Wlin[64 + tid]; }
    const float bl0 = blin[0], bl1 = blin[1];

    const bool lolane = (idx < 4);
    float cc0[2] = {0.f, 0.f};    // L0 cell per local pair (A in quad0, B in quad1)
    float cc1[2] = {0.f, 0.f};

    __syncthreads();

    for (int p = 0; p < NPH2; ++p) {
        const int par = p & 1;
        const float* X0r = &X0[par ^ 1][0][idx * 8];
        const float* X1r = &X1[par ^ 1][0][idx * 8];
        float* X0w = &X0[par][0][j];
        float* X1w = &X1[par][0][j];

        const int gs = p & 7;                              // finishing global slot (p>=8)
        const bool prodBlk = (p >= 8) && ((gs >> 2) == half);

        float QM[2][8];   // L0 bias + Whh0.h0 accumulators, live across barriers

        // ======== REGION A + conditional early post ========
        REGA(0)
        if (prodBlk && ((gs >> 1) & 1) == 0) {
            __syncthreads();          // midbar: finishing pair (0)'s X1 visible
            DO_PRODUCE()
        }
        REGA(1)
        if (prodBlk && ((gs >> 1) & 1) == 1) {
            __syncthreads();          // midbar: finishing pair (1)'s X1 visible
            DO_PRODUCE()
        }

        // ======== consumer: single-thread spin (no barrier needed before it) ========
        if (p >= 8 && !prodBlk && tid == 0) {
            const int w1 = p - 8;
            u64* rp = ring + ((size_t)row * 16 + (p & 15)) * 2;
            const unsigned tag = (unsigned)(p + 1);
            u64 va, vb;
            do { va = __hip_atomic_load(&rp[0], __ATOMIC_ACQUIRE, __HIP_MEMORY_SCOPE_AGENT);
            } while ((unsigned)(va >> 32) != tag);
            do { vb = __hip_atomic_load(&rp[1], __ATOMIC_ACQUIRE, __HIP_MEMORY_SCOPE_AGENT);
            } while ((unsigned)(vb >> 32) != tag);
            outr[w1 & 7][0] = __uint_as_float((unsigned)va);
            outr[w1 & 7][1] = __uint_as_float((unsigned)vb);
        }
        __syncthreads();                 // bar2: outr[(p-8)&7] + all X1 writes visible

        // ======== REGION C: rank-2 x-feedback + L0 TAILs ========
        float xs0, xs1, xs2, xs3;
        if (p >= 15) {
            const float xc = xsel4(trajS[p*4+0], trajS[p*4+1],
                                   outr[p & 7][0], outr[p & 7][1], q2);
            xs0 = xs1 = xs2 = xs3 = xc;
        } else {
            float t[4];
            #pragma unroll
            for (int c = 0; c < 4; ++c) {
                const int g = 4*half + c;
                const int s = (p - g) & 7;
                const int w = p - s;
                t[c] = ((unsigned)w < (unsigned)NW) ? xload(trajS, outr, w, s, q2) : 0.f;
            }
            xs0 = t[0]; xs1 = t[1]; xs2 = t[2]; xs3 = t[3];
        }
        #pragma unroll
        for (int P = 0; P < 2; ++P) {
            const int cA = 4*half + 2*P, cB = cA + 1;
            const int lA = 2*P,          lB = lA + 1;
            const int sA0 = (p - cA) & 7, sB0 = (p - cB) & 7;
            const bool vA0 = (unsigned)(p - sA0) < (unsigned)NW;
            const bool vB0 = (unsigned)(p - sB0) < (unsigned)NW;
            const float xA = P ? xs2 : xs0;
            const float xB = P ? xs3 : xs1;
            float Q0 = fmaf(wx0, xA, QM[P][0]);
            float Q1 = fmaf(wx1, xA, QM[P][1]);
            float Q2 = fmaf(wx2, xA, QM[P][2]);
            float Q3 = fmaf(wx3, xA, QM[P][3]);
            float Q4 = fmaf(wx0, xB, QM[P][4]);
            float Q5 = fmaf(wx1, xB, QM[P][5]);
            float Q6 = fmaf(wx2, xB, QM[P][6]);
            float Q7 = fmaf(wx3, xB, QM[P][7]);
            float hn0;
            TAIL8(cc0[P], sA0, sB0, vA0, vB0, hn0)
            if (vA0 && idx == 0) X0w[lA*64] = hn0;
            if (vB0 && idx == 4) X0w[lB*64] = hn0;
        }
        __syncthreads();                 // bar3: h0(p) visible for next phase
    }

    // ---- final hidden/cell state: window NW-1 = global slot 7 -> half 1, local slot 3 ----
    // h0 final written phase 254 (par 0); h1 final phase 255 (par 1). Pair P=1, B-side -> hi quad.
    if (half == 1 && idx == 4) {
        float* hn = out + (size_t)NB * NW * 2;
        float* cn = hn + 2 * NB * 64;
        hn[(0 * NB + row) * 64 + j] = X0[0][3][j];
        hn[(1 * NB + row) * 64 + j] = X1[1][3][j];
        cn[(0 * NB + row) * 64 + j] = cc0[1];
        cn[(1 * NB + row) * 64 + j] = cc1[1];
    }
}

extern "C" void kernel_launch(void* const* d_in, const int* in_sizes, int n_in,
                              void* d_out, int out_size, void* d_ws, size_t ws_size,
                              hipStream_t stream) {
    const float* traj = (const float*)d_in[0];
    const float* Wih0 = (const float*)d_in[1];
    const float* Whh0 = (const float*)d_in[2];
    const float* bih0 = (const float*)d_in[3];
    const float* bhh0 = (const float*)d_in[4];
    const float* Wih1 = (const float*)d_in[5];
    const float* Whh1 = (const float*)d_in[6];
    const float* bih1 = (const float*)d_in[7];
    const float* bhh1 = (const float*)d_in[8];
    const float* Wlin = (const float*)d_in[9];
    const float* blin = (const float*)d_in[10];
    float* out = (float*)d_out;

    // workspace: ring = u64[64 rows][16 slots][2] (16 KB), tag-embedded values.
    u64* ring = (u64*)d_ws;
    // zero tags every launch (graph-captured -> re-runs on every replay); first tag used is 9.
    hipMemsetAsync(d_ws, 0, (size_t)NB * 16 * 2 * sizeof(u64), stream);

    void* kargs[] = { (void*)&traj, (void*)&Wih0, (void*)&Whh0, (void*)&bih0, (void*)&bhh0,
                      (void*)&Wih1, (void*)&Whh1, (void*)&bih1, (void*)&bhh1,
                      (void*)&Wlin, (void*)&blin, (void*)&out, (void*)&ring };
    hipLaunchCooperativeKernel((const void*)or_lstm_coop, dim3(NB * 2), dim3(512),
                               kargs, 0, stream);
}

// Round 21
// 955.580 us; speedup vs baseline: 1.0175x; 1.0175x over previous
//
#include <hip/hip_runtime.h>
#include <math.h>

typedef float4 f4;
typedef unsigned long long u64;
typedef __attribute__((ext_vector_type(2))) float v2f;
typedef __attribute__((ext_vector_type(4))) float v4f;
#define NW 248
#define NB 64
#define NPH2 (NW + 8)   // 256 phases; phase p: L0 step p, L1 step p-1 (window-parallel, split 2 blocks/row)

// ============================================================================
// FINAL CHAMPION (r18, 883us core; session 1984 -> 883, 2.25x).
// Structure: 248 overlapping windows, 8 in flight staggered 1 step/phase; each
// row split across 2 blocks (4 slots each); cross-block coupling = out[p-8]
// (2 floats/phase) via tagged-u64 ring; packed-FP32 (v_pk_fma_f32) dots.
// Complete failure catalog (all measured; do NOT retry):
//  - r8:  >1 spinner thread/block on agent atomics -> coherent-poll storm (16x).
//  - r10: 4 blocks/row -> exchange exposure doubles, 1692us.
//  - r11: RELAXED atomic spin-loads lower to per-poll writes (WRITE_SIZE 15MB).
//  - r11/r12: 3x-duplicated region-A -> VGPR 128 + scratch spill (+40%).
//  - r13: producer-only bar1 / post reorder: neutral-negative (945).
//  - r14/r16: 1024thr: both occupancy knobs (amdgpu_waves_per_eu(4,4),
//    __launch_bounds__(1024,4)) rejected -> 64-VGPR provision, total spill.
//    Weight-resident design locked to 512 threads / 2 waves per SIMD.
//  - r20: conditional early-post (midbar inside region A): +2.8% (908) —
//    the midbar breaks REGA(0)||REGA(1) scheduling overlap; clean counters,
//    idea falsified independent of r12's spill confound.
// Remaining stall (~4.7K cyc/phase) = 8-wave lockstep barrier convergence at
// 2 waves/SIMD + L2 exchange; every measured neighbor regresses. Not a HW
// roofline (HBM 0.06%, VALU ~45% active) — the floor of this decomposition.
// ============================================================================

__device__ __forceinline__ float tanh_f(float x) { return 2.0f * __builtin_amdgcn_rcpf(1.0f + __expf(-2.0f * x)) - 1.0f; }

template<int CTRL>
__device__ __forceinline__ float dppf(float v) {
    return __int_as_float(__builtin_amdgcn_update_dpp(0, __float_as_int(v), CTRL, 0xF, 0xF, true));
}
#define XOR1 0xB1   // quad_perm [1,0,3,2]
#define XOR2 0x4E   // quad_perm [2,3,0,1]
#define MIR7 0x141  // ROW_HALF_MIRROR: lane i -> 7-i within 8 (== xor 7)
#define BC0  0x00
#define BC1  0x55
#define BC2  0xAA
#define BC3  0xFF

#define OPQ1(X) asm volatile("" : "+v"(X));

// packed fp32 fma: acc.x += W.x*H.x; acc.y += W.y*H.y  (v_pk_fma_f32)
#define PFMA(acc,W,H) (acc) = __builtin_elementwise_fma((W), (H), (acc));
#define DOTG(N,h0,h1,h2,h3,ACC) \
  PFMA(ACC, N##0, h0) PFMA(ACC, N##1, h1) PFMA(ACC, N##2, h2) PFMA(ACC, N##3, h3)

#define LO2(V) __builtin_shufflevector((V), (V), 0, 1)
#define HI2(V) __builtin_shufflevector((V), (V), 2, 3)

#define LDW2(N, SRC, G) \
  v2f N##0 = *(const v2f*)((SRC) + (G)*4096 + jo),     \
      N##1 = *(const v2f*)((SRC) + (G)*4096 + jo + 2), \
      N##2 = *(const v2f*)((SRC) + (G)*4096 + jo + 4), \
      N##3 = *(const v2f*)((SRC) + (G)*4096 + jo + 6);
#define OPQW(N) OPQ1(N##0) OPQ1(N##1) OPQ1(N##2) OPQ1(N##3)

// Butterfly (verified invariant: reg m holds value (m&3)^q2, half bit2(m)) +
// unified activation + cell update. Uses Q0..Q7, lolane, fs2, fs3, kae from scope.
#define TAIL8(CC, SA, SB, VA, VB, HN)                                                     \
    {                                                                                     \
        float r0=dppf<XOR1>(Q1), r1=dppf<XOR1>(Q0), r2=dppf<XOR1>(Q3), r3=dppf<XOR1>(Q2); \
        float r4=dppf<XOR1>(Q5), r5=dppf<XOR1>(Q4), r6=dppf<XOR1>(Q7), r7=dppf<XOR1>(Q6); \
        Q0+=r0; Q1+=r1; Q2+=r2; Q3+=r3; Q4+=r4; Q5+=r5; Q6+=r6; Q7+=r7;                   \
        float u0=dppf<XOR2>(Q2), u3=dppf<XOR2>(Q1), u4=dppf<XOR2>(Q6), u7=dppf<XOR2>(Q5); \
        Q0+=u0; Q3+=u3; Q4+=u4; Q7+=u7;                                                   \
        float m0=dppf<MIR7>(Q3), m4=dppf<MIR7>(Q7);                                       \
        Q0+=m0; Q4+=m4;                                                                   \
        const float yv = lolane ? Q0 : Q4;                                                \
        const float av = fmaf(fs2, __builtin_amdgcn_rcpf(1.f + __expf(kae*yv)), fs3);     \
        const float gi = dppf<BC0>(av);                                                   \
        const float gf = dppf<BC1>(av);                                                   \
        const float gg = dppf<BC2>(av);                                                   \
        const float go = dppf<BC3>(av);                                                   \
        const bool rst = lolane ? ((SA)==0) : ((SB)==0);                                  \
        const bool upd = lolane ? (VA) : (VB);                                            \
        const float igv = gi * gg;                                                        \
        const float ccn = rst ? igv : fmaf(gf, CC, igv);                                  \
        CC = upd ? ccn : CC;                                                              \
        HN = go * tanh_f(CC);                                                             \
    }

__device__ __forceinline__ float xsel4(float x0, float x1, float x2, float x3, int q2) {
    return (q2 & 2) ? ((q2 & 1) ? x3 : x2) : ((q2 & 1) ? x1 : x0);
}

// General (prologue) x-sourcing. Every outr read is row (w+s-8)&7 == (p-8)&7.
__device__ __forceinline__ float xload(const float* trajS, const float (*outr)[2],
                                       int w, int s, int q2) {
    float x0, x1, x2, x3;
    if (w == 0) {
        x0 = trajS[s*4+0]; x1 = trajS[s*4+1]; x2 = trajS[s*4+2]; x3 = trajS[s*4+3];
    } else if (w < 8) {
        if (s < 8 - w) {
            const int tt = w + s;
            x0 = trajS[tt*4+0]; x1 = trajS[tt*4+1]; x2 = trajS[tt*4+2]; x3 = trajS[tt*4+3];
        } else {
            const int tc = 2*w + s - 1;
            const int jo2 = (w + s - 8) & 7;
            x0 = trajS[tc*4+0]; x1 = trajS[tc*4+1];
            x2 = outr[jo2][0];  x3 = outr[jo2][1];
        }
    } else {
        const int tc = w + s;
        const int jo2 = (w + s) & 7;
        x0 = trajS[tc*4+0]; x1 = trajS[tc*4+1];
        x2 = outr[jo2][0];  x3 = outr[jo2][1];
    }
    return xsel4(x0, x1, x2, x3, q2);
}

// 2 blocks per row. SAME-XCD PAIRING: row = bid&63, half = bid>>6 (pair r, r+64
// both == r mod 8 -> same XCD under round-robin; perf heuristic only).
// Exchange = out[p-8] as TWO tagged u64 atomics {tag=p+1, f32}; ONE spinner/block.
__global__ __launch_bounds__(512) __attribute__((amdgpu_waves_per_eu(2, 2)))
void or_lstm_coop(const float* __restrict__ traj,
                  const float* __restrict__ Wih0, const float* __restrict__ Whh0,
                  const float* __restrict__ bih0, const float* __restrict__ bhh0,
                  const float* __restrict__ Wih1, const float* __restrict__ Whh1,
                  const float* __restrict__ bih1, const float* __restrict__ bhh1,
                  const float* __restrict__ Wlin, const float* __restrict__ blin,
                  float* __restrict__ out, u64* __restrict__ ring)
{
    const int bid  = blockIdx.x;
    const int row  = bid & 63;
    const int half = bid >> 6;        // 0: slots 0-3, 1: slots 4-7  (pair on same XCD)
    const int tid  = threadIdx.x;     // = j*8 + idx
    const int j    = tid >> 3;
    const int idx  = tid & 7;
    const int q2   = idx & 3;

    __shared__ __align__(16) float trajS[256 * 4];
    __shared__ __align__(16) float X0[2][4][64];   // [parity][local slot][j]
    __shared__ __align__(16) float X1[2][4][64];
    __shared__ float outr[8][2];                   // full ring, mirrored in both blocks

    if (tid < 256)
        ((f4*)trajS)[tid] = ((const f4*)(traj + (size_t)row * 256 * 4))[tid];
    ((float*)X0)[tid] = 0.f;                       // 2*4*64 = 512 floats each
    ((float*)X1)[tid] = 0.f;

    // ---- gate-permuted weight slices as v2 pairs (identical in both blocks) ----
    const int jo = j * 64 + idx * 8;
    const int v0 = q2, v1 = 1 ^ q2, v2 = 2 ^ q2, v3 = 3 ^ q2;
    LDW2(W0, Whh0, v0) LDW2(W1, Whh0, v1) LDW2(W2, Whh0, v2) LDW2(W3, Whh0, v3)
    LDW2(U0, Wih1, v0) LDW2(U1, Wih1, v1) LDW2(U2, Wih1, v2) LDW2(U3, Wih1, v3)
    LDW2(V0, Whh1, v0) LDW2(V1, Whh1, v1) LDW2(V2, Whh1, v2) LDW2(V3, Whh1, v3)
    OPQW(W0) OPQW(W1) OPQW(W2) OPQW(W3)
    OPQW(U0) OPQW(U1) OPQW(U2) OPQW(U3)
    OPQW(V0) OPQW(V1) OPQW(V2) OPQW(V3)

    float wx0 = (idx < 4) ? Wih0[v0*256 + j*4 + q2] : 0.f;
    float wx1 = (idx < 4) ? Wih0[v1*256 + j*4 + q2] : 0.f;
    float wx2 = (idx < 4) ? Wih0[v2*256 + j*4 + q2] : 0.f;
    float wx3 = (idx < 4) ? Wih0[v3*256 + j*4 + q2] : 0.f;
    float bb00 = (idx == 0) ? (bih0[0*64+j] + bhh0[0*64+j]) : 0.f;
    float bb01 = (idx == 0) ? (bih0[1*64+j] + bhh0[1*64+j]) : 0.f;
    float bb02 = (idx == 0) ? (bih0[2*64+j] + bhh0[2*64+j]) : 0.f;
    float bb03 = (idx == 0) ? (bih0[3*64+j] + bhh0[3*64+j]) : 0.f;
    float bb10 = (idx == 0) ? (bih1[0*64+j] + bhh1[0*64+j]) : 0.f;
    float bb11 = (idx == 0) ? (bih1[1*64+j] + bhh1[1*64+j]) : 0.f;
    float bb12 = (idx == 0) ? (bih1[2*64+j] + bhh1[2*64+j]) : 0.f;
    float bb13 = (idx == 0) ? (bih1[3*64+j] + bhh1[3*64+j]) : 0.f;
    OPQ1(wx0) OPQ1(wx1) OPQ1(wx2) OPQ1(wx3)
    OPQ1(bb00) OPQ1(bb01) OPQ1(bb02) OPQ1(bb03)
    OPQ1(bb10) OPQ1(bb11) OPQ1(bb12) OPQ1(bb13)

    const float kae = (q2 == 2) ? -2.f : -1.f;
    const float fs2 = (q2 == 2) ?  2.f :  1.f;
    const float fs3 = (q2 == 2) ? -1.f :  0.f;

    // epilogue weights: wave 0 computes BOTH output components
    float wl0 = 0.f, wl1 = 0.f;
    if (tid < 64) { wl0 = Wlin[tid]; wl1 = Wlin[64 + tid]; }
    const float bl0 = blin[0], bl1 = blin[1];

    const bool lolane = (idx < 4);
    float cc0[2] = {0.f, 0.f};    // L0 cell per local pair (A in quad0, B in quad1)
    float cc1[2] = {0.f, 0.f};

    __syncthreads();

    for (int p = 0; p < NPH2; ++p) {
        const int par = p & 1;
        const float* X0r = &X0[par ^ 1][0][idx * 8];
        const float* X1r = &X1[par ^ 1][0][idx * 8];
        float* X0w = &X0[par][0][j];
        float* X1w = &X1[par][0][j];

        float QM[2][8];   // L0 bias + Whh0.h0 accumulators, live across barriers

        // ======== REGION A: L1(p-1) full + L0(p) h-part, own 2 pairs ========
        #pragma unroll
        for (int P = 0; P < 2; ++P) {
            const int cA = 4*half + 2*P, cB = cA + 1;    // global slots
            const int lA = 2*P,          lB = lA + 1;    // local slots
            const int sA0 = (p - cA) & 7,     sB0 = (p - cB) & 7;
            const int sA1 = (p - 1 - cA) & 7, sB1 = (p - 1 - cB) & 7;
            const bool vA1 = (unsigned)(p - 1 - sA1) < (unsigned)NW;
            const bool vB1 = (unsigned)(p - 1 - sB1) < (unsigned)NW;

            // h0(p-1) slices (v2) — feed both L0 W-dot and L1 U-dot
            const v4f hAa = *(const v4f*)(X0r + lA*64), hAb = *(const v4f*)(X0r + lA*64 + 4);
            const v4f hBa = *(const v4f*)(X0r + lB*64), hBb = *(const v4f*)(X0r + lB*64 + 4);
            const v2f hA0 = LO2(hAa), hA1 = HI2(hAa), hA2 = LO2(hAb), hA3 = HI2(hAb);
            const v2f hB0 = LO2(hBa), hB1 = HI2(hBa), hB2 = LO2(hBb), hB3 = HI2(hBb);

            {   // L0 main gates (bias + Whh0.h0; x added in region C) — packed
                v2f a0 = {bb00, 0.f}, a1 = {bb01, 0.f}, a2 = {bb02, 0.f}, a3 = {bb03, 0.f};
                v2f a4 = {bb00, 0.f}, a5 = {bb01, 0.f}, a6 = {bb02, 0.f}, a7 = {bb03, 0.f};
                if (sA0 != 0) {
                    DOTG(W0, hA0,hA1,hA2,hA3, a0)
                    DOTG(W1, hA0,hA1,hA2,hA3, a1)
                    DOTG(W2, hA0,hA1,hA2,hA3, a2)
                    DOTG(W3, hA0,hA1,hA2,hA3, a3)
                }
                if (sB0 != 0) {
                    DOTG(W0, hB0,hB1,hB2,hB3, a4)
                    DOTG(W1, hB0,hB1,hB2,hB3, a5)
                    DOTG(W2, hB0,hB1,hB2,hB3, a6)
                    DOTG(W3, hB0,hB1,hB2,hB3, a7)
                }
                QM[P][0]=a0.x+a0.y; QM[P][1]=a1.x+a1.y; QM[P][2]=a2.x+a2.y; QM[P][3]=a3.x+a3.y;
                QM[P][4]=a4.x+a4.y; QM[P][5]=a5.x+a5.y; QM[P][6]=a6.x+a6.y; QM[P][7]=a7.x+a7.y;
            }

            {   // L1 gates: Wih1.h0(p-1) (reuse h slices) + Whh1.h1(p-2) — packed
                v2f p0 = {bb10, 0.f}, p1 = {bb11, 0.f}, p2 = {bb12, 0.f}, p3 = {bb13, 0.f};
                v2f p4 = {bb10, 0.f}, p5 = {bb11, 0.f}, p6 = {bb12, 0.f}, p7 = {bb13, 0.f};
                DOTG(U0, hA0,hA1,hA2,hA3, p0)
                DOTG(U1, hA0,hA1,hA2,hA3, p1)
                DOTG(U2, hA0,hA1,hA2,hA3, p2)
                DOTG(U3, hA0,hA1,hA2,hA3, p3)
                DOTG(U0, hB0,hB1,hB2,hB3, p4)
                DOTG(U1, hB0,hB1,hB2,hB3, p5)
                DOTG(U2, hB0,hB1,hB2,hB3, p6)
                DOTG(U3, hB0,hB1,hB2,hB3, p7)
                if (sA1 != 0) {
                    const v4f eAa = *(const v4f*)(X1r + lA*64), eAb = *(const v4f*)(X1r + lA*64 + 4);
                    const v2f eA0 = LO2(eAa), eA1 = HI2(eAa), eA2 = LO2(eAb), eA3 = HI2(eAb);
                    DOTG(V0, eA0,eA1,eA2,eA3, p0)
                    DOTG(V1, eA0,eA1,eA2,eA3, p1)
                    DOTG(V2, eA0,eA1,eA2,eA3, p2)
                    DOTG(V3, eA0,eA1,eA2,eA3, p3)
                }
                if (sB1 != 0) {
                    const v4f eBa = *(const v4f*)(X1r + lB*64), eBb = *(const v4f*)(X1r + lB*64 + 4);
                    const v2f eB0 = LO2(eBa), eB1 = HI2(eBa), eB2 = LO2(eBb), eB3 = HI2(eBb);
                    DOTG(V0, eB0,eB1,eB2,eB3, p4)
                    DOTG(V1, eB0,eB1,eB2,eB3, p5)
                    DOTG(V2, eB0,eB1,eB2,eB3, p6)
                    DOTG(V3, eB0,eB1,eB2,eB3, p7)
                }
                float Q0 = p0.x+p0.y, Q1 = p1.x+p1.y, Q2 = p2.x+p2.y, Q3 = p3.x+p3.y;
                float Q4 = p4.x+p4.y, Q5 = p5.x+p5.y, Q6 = p6.x+p6.y, Q7 = p7.x+p7.y;
                float hn1;
                TAIL8(cc1[P], sA1, sB1, vA1, vB1, hn1)
                if (vA1 && idx == 0) X1w[lA*64] = hn1;
                if (vB1 && idx == 4) X1w[lB*64] = hn1;
            }
        }
        __syncthreads();                 // bar1: h1(p-1) visible (incl. finishing window p-8)

        // ======== REGION B: out[p-8] — produce (owner) / receive (single spinner) ========
        if (p >= 8) {
            const int w1 = p - 8;
            const int gs = p & 7;                                  // finishing global slot
            u64* rp = ring + ((size_t)row * 16 + (p & 15)) * 2;
            const unsigned tag = (unsigned)(p + 1);
            if ((gs >> 2) == half) {
                // producer: wave 0 computes both Wlin dots from own X1 slot
                if (tid < 64) {
                    const float hval = X1[par][gs & 3][tid];
                    float r0 = wl0 * hval, r1 = wl1 * hval;
                    #pragma unroll
                    for (int off = 32; off > 0; off >>= 1) {
                        r0 += __shfl_down(r0, off);
                        r1 += __shfl_down(r1, off);
                    }
                    if (tid == 0) {
                        const float prev0 = w1 ? outr[(w1-1) & 7][0] : trajS[7*4+2];
                        const float prev1 = w1 ? outr[(w1-1) & 7][1] : trajS[7*4+3];
                        const float o0 = prev0 + r0 + bl0;
                        const float o1 = prev1 + r1 + bl1;
                        outr[w1 & 7][0] = o0; outr[w1 & 7][1] = o1;
                        out[((size_t)row * NW + w1) * 2 + 0] = o0;
                        out[((size_t)row * NW + w1) * 2 + 1] = o1;
                        const u64 pk0 = ((u64)tag << 32) | (u64)__float_as_uint(o0);
                        const u64 pk1 = ((u64)tag << 32) | (u64)__float_as_uint(o1);
                        __hip_atomic_store(&rp[0], pk0, __ATOMIC_RELEASE, __HIP_MEMORY_SCOPE_AGENT);
                        __hip_atomic_store(&rp[1], pk1, __ATOMIC_RELEASE, __HIP_MEMORY_SCOPE_AGENT);
                    }
                }
            } else {
                // consumer: exactly ONE thread spins, fills the LDS ring
                if (tid == 0) {
                    u64 va, vb;
                    do { va = __hip_atomic_load(&rp[0], __ATOMIC_ACQUIRE, __HIP_MEMORY_SCOPE_AGENT);
                    } while ((unsigned)(va >> 32) != tag);
                    do { vb = __hip_atomic_load(&rp[1], __ATOMIC_ACQUIRE, __HIP_MEMORY_SCOPE_AGENT);
                    } while ((unsigned)(vb >> 32) != tag);
                    outr[w1 & 7][0] = __uint_as_float((unsigned)va);
                    outr[w1 & 7][1] = __uint_as_float((unsigned)vb);
                }
            }
        }
        __syncthreads();                 // bar2: outr[(p-8)&7] visible

        // ======== REGION C: rank-2 x-feedback + L0 TAILs ========
        float xs0, xs1, xs2, xs3;
        if (p >= 15) {
            const float xc = xsel4(trajS[p*4+0], trajS[p*4+1],
                                   outr[p & 7][0], outr[p & 7][1], q2);
            xs0 = xs1 = xs2 = xs3 = xc;
        } else {
            float t[4];
            #pragma unroll
            for (int c = 0; c < 4; ++c) {
                const int g = 4*half + c;
                const int s = (p - g) & 7;
                const int w = p - s;
                t[c] = ((unsigned)w < (unsigned)NW) ? xload(trajS, outr, w, s, q2) : 0.f;
            }
            xs0 = t[0]; xs1 = t[1]; xs2 = t[2]; xs3 = t[3];
        }
        #pragma unroll
        for (int P = 0; P < 2; ++P) {
            const int cA = 4*half + 2*P, cB = cA + 1;
            const int lA = 2*P,          lB = lA + 1;
            const int sA0 = (p - cA) & 7, sB0 = (p - cB) & 7;
            const bool vA0 = (unsigned)(p - sA0) < (unsigned)NW;
            const bool vB0 = (unsigned)(p - sB0) < (unsigned)NW;
            const float xA = P ? xs2 : xs0;
            const float xB = P ? xs3 : xs1;
            float Q0 = fmaf(wx0, xA, QM[P][0]);
            float Q1 = fmaf(wx1, xA, QM[P][1]);
            float Q2 = fmaf(wx2, xA, QM[P][2]);
            float Q3 = fmaf(wx3, xA, QM[P][3]);
            float Q4 = fmaf(wx0, xB, QM[P][4]);
            float Q5 = fmaf(wx1, xB, QM[P][5]);
            float Q6 = fmaf(wx2, xB, QM[P][6]);
            float Q7 = fmaf(wx3, xB, QM[P][7]);
            float hn0;
            TAIL8(cc0[P], sA0, sB0, vA0, vB0, hn0)
            if (vA0 && idx == 0) X0w[lA*64] = hn0;
            if (vB0 && idx == 4) X0w[lB*64] = hn0;
        }
        __syncthreads();                 // bar3: h0(p) visible for next phase
    }

    // ---- final hidden/cell state: window NW-1 = global slot 7 -> half 1, local slot 3 ----
    // h0 final written phase 254 (par 0); h1 final phase 255 (par 1). Pair P=1, B-side -> hi quad.
    if (half == 1 && idx == 4) {
        float* hn = out + (size_t)NB * NW * 2;
        float* cn = hn + 2 * NB * 64;
        hn[(0 * NB + row) * 64 + j] = X0[0][3][j];
        hn[(1 * NB + row) * 64 + j] = X1[1][3][j];
        cn[(0 * NB + row) * 64 + j] = cc0[1];
        cn[(1 * NB + row) * 64 + j] = cc1[1];
    }
}

extern "C" void kernel_launch(void* const* d_in, const int* in_sizes, int n_in,
                              void* d_out, int out_size, void* d_ws, size_t ws_size,
                              hipStream_t stream) {
    const float* traj = (const float*)d_in[0];
    const float* Wih0 = (const float*)d_in[1];
    const float* Whh0 = (const float*)d_in[2];
    const float* bih0 = (const float*)d_in[3];
    const float* bhh0 = (const float*)d_in[4];
    const float* Wih1 = (const float*)d_in[5];
    const float* Whh1 = (const float*)d_in[6];
    const float* bih1 = (const float*)d_in[7];
    const float* bhh1 = (const float*)d_in[8];
    const float* Wlin = (const float*)d_in[9];
    const float* blin = (const float*)d_in[10];
    float* out = (float*)d_out;

    // workspace: ring = u64[64 rows][16 slots][2] (16 KB), tag-embedded values.
    u64* ring = (u64*)d_ws;
    // zero tags every launch (graph-captured -> re-runs on every replay); first tag used is 9.
    hipMemsetAsync(d_ws, 0, (size_t)NB * 16 * 2 * sizeof(u64), stream);

    void* kargs[] = { (void*)&traj, (void*)&Wih0, (void*)&Whh0, (void*)&bih0, (void*)&bhh0,
                      (void*)&Wih1, (void*)&Whh1, (void*)&bih1, (void*)&bhh1,
                      (void*)&Wlin, (void*)&blin, (void*)&out, (void*)&ring };
    hipLaunchCooperativeKernel((const void*)or_lstm_coop, dim3(NB * 2), dim3(512),
                               kargs, 0, stream);
}